// Round 9
// baseline (125.029 us; speedup 1.0000x reference)
//
#include <hip/hip_runtime.h>
#include <hip/hip_bf16.h>

typedef __attribute__((ext_vector_type(8))) short short8;
typedef __attribute__((ext_vector_type(16))) float floatx16;
typedef __attribute__((ext_vector_type(4))) float floatx4;
typedef __attribute__((ext_vector_type(4))) unsigned uintx4;

template<int N> struct IC { static constexpr int v = N; };

__device__ __forceinline__ short f2bf(float f) {
    unsigned u = __builtin_bit_cast(unsigned, f);
    u += 0x7fffu + ((u >> 16) & 1u);   // RNE
    return (short)(u >> 16);
}

__device__ __forceinline__ unsigned pk_bf16(float lo, float hi) {
    unsigned short a = __builtin_bit_cast(unsigned short, (__bf16)lo);
    unsigned short b = __builtin_bit_cast(unsigned short, (__bf16)hi);
    return (unsigned)a | ((unsigned)b << 16);
}

__device__ __forceinline__ void gload_lds16(const void* g, void* l) {
    __builtin_amdgcn_global_load_lds(
        (const __attribute__((address_space(1))) unsigned*)g,
        (__attribute__((address_space(3))) unsigned*)l, 16, 0, 0);
}

// counted-vmcnt barrier pair (T3/T4): wait own older loads, then join.
__device__ __forceinline__ void bar_vm4() {
    asm volatile("s_waitcnt vmcnt(4)" ::: "memory");
    __builtin_amdgcn_s_barrier();
    __builtin_amdgcn_sched_barrier(0);
}
__device__ __forceinline__ void bar_vm3() {
    asm volatile("s_waitcnt vmcnt(3)" ::: "memory");
    __builtin_amdgcn_s_barrier();
    __builtin_amdgcn_sched_barrier(0);
}
__device__ __forceinline__ void bar_vm0() {
    asm volatile("s_waitcnt vmcnt(0)" ::: "memory");
    __builtin_amdgcn_s_barrier();
    __builtin_amdgcn_sched_barrier(0);
}
__device__ __forceinline__ void bar_raw() {
    __builtin_amdgcn_sched_barrier(0);
    __builtin_amdgcn_s_barrier();
    __builtin_amdgcn_sched_barrier(0);
}

// ---------------------------------------------------------------------------
// f32 -> bf16 convert for x, Wq/Wk/Wv, Wo — one launch. 64-col-tile XOR
// swizzle: 16B chunk cc of dest row holds source chunk cc ^ (drow & 7).
__global__ __launch_bounds__(256)
void conv_all(const float* __restrict__ x, const float* __restrict__ Wq,
              const float* __restrict__ Wk, const float* __restrict__ Wv,
              const float* __restrict__ Wo, short* __restrict__ xb,
              short* __restrict__ wqkv, short* __restrict__ wob) {
    const int bid = blockIdx.x;                // 0..7167
    const float* src; short* dst; int srow, drow;
    if (bid < 2048)      { src = x;  dst = xb;  srow = bid;        drow = bid; }
    else if (bid < 5120) {
        int r = bid - 2048;
        dst = wqkv; drow = r;
        if (r < 2048)      { src = Wq; srow = r; }
        else if (r < 2560) { src = Wk; srow = r - 2048; }
        else               { src = Wv; srow = r - 2560; }
    } else               { src = Wo; dst = wob; srow = bid - 5120; drow = srow; }
    const int c = threadIdx.x;
    const int kt = c >> 3, cc = c & 7;
    const float* s = src + (size_t)srow * 2048 + kt * 64 + (cc ^ (drow & 7)) * 8;
    float4 v0 = *(const float4*)s;
    float4 v1 = *(const float4*)(s + 4);
    short8 o = { f2bf(v0.x), f2bf(v0.y), f2bf(v0.z), f2bf(v0.w),
                 f2bf(v1.x), f2bf(v1.y), f2bf(v1.z), f2bf(v1.w) };
    *(short8*)(dst + (size_t)drow * 2048 + kt * 64 + cc * 8) = o;
}

// ---------------------------------------------------------------------------
// 8-wave bf16 GEMM with 2-deep counted-vmcnt pipeline (T3/T4).
template<int BN, int EPI>
__global__ __launch_bounds__(512, 4)
void gemm8(const short* __restrict__ A, const short* __restrict__ Bw,
           short* __restrict__ qb, short* __restrict__ kb, short* __restrict__ vt,
           float* __restrict__ fout, const float* __restrict__ bias) {
    constexpr int K = 2048;
    constexpr int NN = BN / 32;
    constexpr int ACH = 128 * 8;
    constexpr int NCH = (128 + BN) * 8;
    constexpr int NIT = K / 64;
    __shared__ short sm[2][(128 + BN) * 64];

    const int t = threadIdx.x, lane = t & 63, w = t >> 6;
    const int wm = w & 3, wn = w >> 2;
    const int l15 = lane & 15, lh = lane >> 4;
    const int bn = blockIdx.x, bm = blockIdx.y;
    const int ra0 = bm * 128;
    const short* Bbase = Bw + (size_t)bn * BN * K;

    floatx4 acc[2][NN] = {};

    auto stage = [&](int buf, int k0) {
        short* base = &sm[buf][0];
        #pragma unroll
        for (int i = 0; i < NCH / 512; ++i) {
            int c = i * 512 + t;
            if (c < ACH) {
                int row = c >> 3, cc = c & 7;
                gload_lds16(A + (size_t)(ra0 + row) * K + k0 + cc * 8, base + c * 8);
            } else {
                int c2 = c - ACH;
                int row = c2 >> 3, cc = c2 & 7;
                gload_lds16(Bbase + (size_t)row * K + k0 + cc * 8, base + (ACH + c2) * 8);
            }
        }
    };

    stage(0, 0);
    stage(1, 64);
    #pragma unroll 1
    for (int it = 0; it < NIT; ++it) {
        if (it < NIT - 1) {
            if constexpr (BN == 128) bar_vm4(); else bar_vm3();
        } else bar_vm0();                      // slab `it` ready
        const short* As = &sm[it & 1][0];
        const short* Bs = As + 128 * 64;
        #pragma unroll
        for (int kf = 0; kf < 2; ++kf) {
            short8 a[2], b[NN];
            #pragma unroll
            for (int m = 0; m < 2; ++m) {
                int arow = wm * 32 + m * 16 + l15;
                a[m] = *(const short8*)(As + arow * 64 + (((kf * 4 + lh) ^ (arow & 7)) << 3));
            }
            #pragma unroll
            for (int n = 0; n < NN; ++n) {
                int brow = wn * (BN / 2) + n * 16 + l15;
                b[n] = *(const short8*)(Bs + brow * 64 + (((kf * 4 + lh) ^ (brow & 7)) << 3));
            }
            #pragma unroll
            for (int m = 0; m < 2; ++m)
                #pragma unroll
                for (int n = 0; n < NN; ++n)
                    acc[m][n] = __builtin_amdgcn_mfma_f32_16x16x32_bf16(a[m], b[n], acc[m][n], 0, 0, 0);
        }
        bar_raw();                             // all waves done reading buf it&1
        if (it + 2 < NIT) stage(it & 1, (it + 2) * 64);
    }

    #pragma unroll
    for (int m = 0; m < 2; ++m) {
        #pragma unroll
        for (int n = 0; n < NN; ++n) {
            #pragma unroll
            for (int r = 0; r < 4; ++r) {
                int row = ra0 + wm * 32 + m * 16 + lh * 4 + r;
                int col = bn * BN + wn * (BN / 2) + n * 16 + l15;
                float v = acc[m][n][r];
                if constexpr (EPI == 1) {
                    fout[(size_t)row * 2048 + col] = v + bias[col];
                } else {
                    if (col < 2048) {
                        qb[(size_t)row * 2048 + col] = f2bf(v * 0.18033688011112042f);
                    } else if (col < 2560) {
                        int kcol = col - 2048, within = kcol & 63;
                        int cp = ((within >> 3) ^ (row & 7)) & 7;
                        kb[(size_t)row * 512 + (kcol & ~63) + (cp << 3) + (within & 7)] = f2bf(v);
                    } else {
                        int dg = col - 2560;
                        int cp = (((row >> 3) & 7) ^ (dg & 7)) & 7;
                        vt[(size_t)dg * 2048 + (row & ~63) + (cp << 3) + (row & 7)] = f2bf(v);
                    }
                }
            }
        }
    }
}

// ---------------------------------------------------------------------------
// Causal GQA attention: phase-switch + 2-deep counted-vmcnt pipeline +
// complement pairi swizzle (co-resident blocks get complementary slab counts).
__global__ __launch_bounds__(512, 4)
void attn_fwd(const short* __restrict__ qb, const short* __restrict__ kb,
              const short* __restrict__ vt, short* __restrict__ ob) {
    __shared__ __align__(16) short smem[2][16384];  // per buf: K 128x64 | V^T 64x128

    const int t = threadIdx.x, lane = t & 63, w = t >> 6;
    const int l31 = lane & 31, hi = lane >> 5;
    const int hq = blockIdx.y, hk = hq >> 2;
    // complement swizzle: blocks L and L+256 co-resident -> complementary pairi
    const int pairi = (hq < 16) ? blockIdx.x : 15 - blockIdx.x;
    const int qtA = pairi, qtB = 31 - pairi;
    const int a = w >> 1, p = w & 1;
    const int s = a & 1, h = a >> 1;           // strip, seg2 kv-half
    const int tile1 = (a < 2) ? qtA : qtB;
    const int swl = l31 & 7;

    int rg = tile1 * 64 + s * 32 + l31;        // this lane's current q row

    short8 qf[4];
    {
        const short* qrow = qb + (size_t)rg * 2048 + hq * 64;
        #pragma unroll
        for (int kk = 0; kk < 4; ++kk)
            qf[kk] = *(const short8*)(qrow + kk * 16 + hi * 8);
    }

    float m = -3e38f, l = 0.f;
    floatx16 acc[2] = {};

    auto stage = [&](int buf, int j0) {        // j0 = slab base kv-row (slab * 128)
        short* base = &smem[buf][0];
        #pragma unroll
        for (int i = 0; i < 4; ++i) {
            int c = i * 512 + t;
            if (i < 2) {
                int row = c >> 3, cc = c & 7;
                gload_lds16(kb + (size_t)(j0 + row) * 512 + hk * 64 + cc * 8, base + c * 8);
            } else {
                int cv = c - 1024, drow = cv >> 4, cc = cv & 15;
                gload_lds16(vt + (size_t)(hk * 64 + drow) * 2048 + j0 + cc * 8, base + c * 8);
            }
        }
    };

    auto save_part = [&](float* mb) {
        #pragma unroll
        for (int n = 0; n < 2; ++n)
            #pragma unroll
            for (int r = 0; r < 16; ++r) mb[n * 16 + r] = acc[n][r];
        mb[32] = m;
        mb[33] = l;
    };
    auto merge_part = [&](const float* mb) {
        float m1 = mb[32], l1 = mb[33];
        float M = fmaxf(m, m1);
        float sf0 = __builtin_amdgcn_exp2f(m - M);
        float sf1 = __builtin_amdgcn_exp2f(m1 - M);
        l = sf0 * l + sf1 * l1;
        #pragma unroll
        for (int n = 0; n < 2; ++n)
            #pragma unroll
            for (int r = 0; r < 16; ++r)
                acc[n][r] = sf0 * acc[n][r] + sf1 * mb[n * 16 + r];
        m = M;
    };
    auto writeout = [&](int rgw) {
        const float linv = 1.0f / l;
        const int sw8 = rgw & 7;
        #pragma unroll
        for (int n = 0; n < 2; ++n) {
            #pragma unroll
            for (int g = 0; g < 4; ++g) {
                #pragma unroll
                for (int e = 0; e < 4; e += 2) {
                    int r = 4 * g + e;
                    unsigned pkv = pk_bf16(acc[n][r] * linv, acc[n][r + 1] * linv);
                    int d = 32 * n + e + 8 * g + 4 * hi;
                    int col = hq * 64 + d;
                    int cp = ((col >> 3) & 7) ^ sw8;
                    *(unsigned*)(ob + (size_t)rgw * 2048 + (col & ~63) + (cp << 3) + (col & 7)) = pkv;
                }
            }
        }
    };

    auto process = [&](const short* K0, const short* V0, int blk0, auto NB,
                       int kt, bool diag) {
        constexpr int nblk = decltype(NB)::v;
        floatx16 sT[nblk];
        __builtin_amdgcn_s_setprio(1);
        #pragma unroll
        for (int ib = 0; ib < nblk; ++ib) {
            floatx16 a2 = {};
            const int row = p * 64 + (blk0 + ib) * 32 + l31;
            #pragma unroll
            for (int kk = 0; kk < 4; ++kk) {
                short8 kf = *(const short8*)(K0 + row * 64 + (((2 * kk + hi) ^ swl) << 3));
                a2 = __builtin_amdgcn_mfma_f32_32x32x16_bf16(kf, qf[kk], a2, 0, 0, 0);
            }
            sT[ib] = a2;
        }
        __builtin_amdgcn_s_setprio(0);
        if (diag) {
            #pragma unroll
            for (int ib = 0; ib < nblk; ++ib)
                #pragma unroll
                for (int r = 0; r < 16; ++r) {
                    int jg = kt * 64 + (blk0 + ib) * 32 + (r & 3) + 8 * (r >> 2) + 4 * hi;
                    if (jg > rg) sT[ib][r] = -3e38f;
                }
        }
        float v[16];
        #pragma unroll
        for (int r = 0; r < 16; ++r) {
            v[r] = sT[0][r];
            if constexpr (nblk == 2) v[r] = fmaxf(v[r], sT[1][r]);
        }
        #pragma unroll
        for (int st = 8; st >= 1; st >>= 1)
            #pragma unroll
            for (int r = 0; r < 8; ++r)
                if (r < st) v[r] = fmaxf(v[r], v[r + st]);
        float tm = fmaxf(v[0], __shfl_xor(v[0], 32));

        if (!__all(tm <= m + 8.0f)) {
            float mn = fmaxf(m, tm);
            float sf = __builtin_amdgcn_exp2f(m - mn);
            m = mn;
            l *= sf;
            #pragma unroll
            for (int n = 0; n < 2; ++n)
                #pragma unroll
                for (int r = 0; r < 16; ++r) acc[n][r] *= sf;
        }

        float sv[16];
        #pragma unroll
        for (int ib = 0; ib < nblk; ++ib)
            #pragma unroll
            for (int r = 0; r < 16; ++r)
                sT[ib][r] = __builtin_amdgcn_exp2f(sT[ib][r] - m);
        #pragma unroll
        for (int r = 0; r < 16; ++r) {
            sv[r] = sT[0][r];
            if constexpr (nblk == 2) sv[r] += sT[1][r];
        }
        #pragma unroll
        for (int st = 8; st >= 1; st >>= 1)
            #pragma unroll
            for (int r = 0; r < 8; ++r)
                if (r < st) sv[r] += sv[r + st];
        l += sv[0] + __shfl_xor(sv[0], 32);

        #pragma unroll
        for (int ib = 0; ib < nblk; ++ib) {
            unsigned Qd[8], Pd[8];
            #pragma unroll
            for (int c = 0; c < 8; ++c)
                Qd[c] = pk_bf16(sT[ib][2 * c], sT[ib][2 * c + 1]);
            #pragma unroll
            for (int c = 0; c < 8; ++c)
                Pd[c] = __shfl_xor(Qd[c], 32);
            __builtin_amdgcn_s_setprio(1);
            #pragma unroll
            for (int b = 0; b < 2; ++b) {
                uintx4 j;
                if (b == 0) {
                    j.x = hi ? Pd[2] : Qd[0];
                    j.y = hi ? Pd[3] : Qd[1];
                    j.z = hi ? Qd[2] : Pd[0];
                    j.w = hi ? Qd[3] : Pd[1];
                } else {
                    j.x = hi ? Pd[6] : Qd[4];
                    j.y = hi ? Pd[7] : Qd[5];
                    j.z = hi ? Qd[6] : Pd[4];
                    j.w = hi ? Qd[7] : Pd[5];
                }
                short8 pf = __builtin_bit_cast(short8, j);
                const int kk = (blk0 + ib) * 2 + b;
                const int ch = p * 64 + (((2 * kk + hi) ^ swl) << 3);
                short8 vf0 = *(const short8*)(V0 + l31 * 128 + ch);
                acc[0] = __builtin_amdgcn_mfma_f32_32x32x16_bf16(vf0, pf, acc[0], 0, 0, 0);
                short8 vf1 = *(const short8*)(V0 + (32 + l31) * 128 + ch);
                acc[1] = __builtin_amdgcn_mfma_f32_32x32x16_bf16(vf1, pf, acc[1], 0, 0, 0);
            }
            __builtin_amdgcn_s_setprio(0);
        }
    };

    const int ss_tr = (qtA >> 1) + 1;
    const int nss = (qtB >> 1) + 1;

    // ---- prologue: stage 2 slabs (slab ss_tr+1 deliberately NOT staged in
    //      seg1 — its buffer is the transition merge scratch)
    stage(0, 0);
    stage(1, 128);

    // ---- segment 1
    #pragma unroll 1
    for (int ss = 0; ss < ss_tr; ++ss) {
        if (ss < nss - 1) bar_vm4(); else bar_vm0();   // slab ss ready
        const int kt = 2 * ss + p;
        if (kt <= tile1)
            process(&smem[ss & 1][0], &smem[ss & 1][8192], 0, IC<2>{}, kt, kt == tile1);
        bar_raw();                                     // done reading buf ss&1
        if (ss + 2 < nss && ss + 2 != ss_tr + 1) stage(ss & 1, (ss + 2) * 128);
    }

    // ---- transition: drain; merge A via the unstaged buffer; re-arm; re-stage
    __syncthreads();                                   // vm+lgkm drain, all waves
    {
        float* msc = (float*)&smem[(ss_tr + 1) & 1][0];
        if (a < 2 && p == 1) save_part(msc + (s * 64 + lane) * 34);
        __syncthreads();
        if (a < 2 && p == 0) {
            merge_part(msc + (s * 64 + lane) * 34);
            writeout(rg);
        }
        if (a < 2) {
            rg = qtB * 64 + s * 32 + l31;
            const short* qrow = qb + (size_t)rg * 2048 + hq * 64;
            #pragma unroll
            for (int kk = 0; kk < 4; ++kk)
                qf[kk] = *(const short8*)(qrow + kk * 16 + hi * 8);
            m = -3e38f;
            l = 0.f;
            acc[0] = (floatx16){};
            acc[1] = (floatx16){};
        }
        __syncthreads();                               // merge reads done
        if (ss_tr + 1 < nss) stage((ss_tr + 1) & 1, (ss_tr + 1) * 128);
    }

    // ---- segment 2: all 8 waves on tile B, 32-kv-row sub-tiles
    #pragma unroll 1
    for (int ss = ss_tr; ss < nss; ++ss) {
        if (ss < nss - 1) bar_vm4(); else bar_vm0();   // slab ss ready
        const int kt = 2 * ss + p;
        if (kt <= qtB)
            process(&smem[ss & 1][0], &smem[ss & 1][8192], h, IC<1>{}, kt, kt == qtB);
        bar_raw();
        if (ss + 2 < nss) stage(ss & 1, (ss + 2) * 128);
    }

    // ---- end: merge 4 partials per B strip (2 LDS steps)
    __syncthreads();
    float* msc = (float*)&smem[0][0];
    if (p == 1) save_part(msc + (a * 64 + lane) * 34);
    __syncthreads();
    if (p == 0) merge_part(msc + (a * 64 + lane) * 34);
    __syncthreads();
    if (p == 0 && a >= 2) save_part(msc + ((a & 1) * 64 + lane) * 34);
    __syncthreads();
    if (p == 0 && a < 2) {
        merge_part(msc + (a * 64 + lane) * 34);
        writeout(rg);
    }
}

// ---------------------------------------------------------------------------
extern "C" void kernel_launch(void* const* d_in, const int* in_sizes, int n_in,
                              void* d_out, int out_size, void* d_ws, size_t ws_size,
                              hipStream_t stream) {
    const float* x  = (const float*)d_in[0];
    const float* Wq = (const float*)d_in[1];
    const float* Wk = (const float*)d_in[2];
    const float* Wv = (const float*)d_in[3];
    const float* Wo = (const float*)d_in[4];
    const float* bo = (const float*)d_in[5];

    char* ws = (char*)d_ws;
    short* xb   = (short*)ws;                            // 8 MiB (reused as ob)
    short* wqkv = (short*)(ws + ((size_t)8  << 20));     // 12 MiB
    short* qb   = (short*)(ws + ((size_t)20 << 20));     // 8 MiB
    short* kb   = (short*)(ws + ((size_t)28 << 20));     // 2 MiB (attn-swizzled)
    short* vt   = (short*)(ws + ((size_t)30 << 20));     // 2 MiB (V^T, attn-swizzled)
    short* wob  = (short*)(ws + ((size_t)32 << 20));     // 8 MiB
    short* ob   = xb;      // x dead after QKV GEMM

    conv_all<<<7168, 256, 0, stream>>>(x, Wq, Wk, Wv, Wo, xb, wqkv, wob);
    gemm8<128, 0><<<dim3(24, 16), 512, 0, stream>>>(xb, wqkv, qb, kb, vt, nullptr, nullptr);
    attn_fwd<<<dim3(16, 32), 512, 0, stream>>>(qb, kb, vt, ob);
    gemm8<64, 1><<<dim3(32, 16), 512, 0, stream>>>(ob, wob, nullptr, nullptr, nullptr,
                                                   (float*)d_out, bo);
}